// Round 15
// baseline (49.030 us; speedup 1.0000x reference)
//
#include <hip/hip_runtime.h>
#include <math.h>

typedef unsigned int u32;
typedef unsigned long long u64;

#define N_ELEM 131072
#define NBIN 16384         // uniform VALUE bins over [-5.2, 5.2]
#define NW (NBIN / 32)     // occupancy words (512) == BS: thread t <-> word t
#define XMIN (-5.2)
#define XMAX (5.2)
#define BINW (10.4 / 16384.0)       // 6.348e-4; vertex gap 0.1 spans >=157 bins
#define INVW ((float)(16384.0 / 10.4))
#define CAP 1024           // threshold capacity per array (typ. ~300 used)
#define GRID 128           // persistent blocks (<= 256 CUs -> co-resident)
#define BS 512             // threads per block (8 waves)
#define EPB 2048           // elements per block in data phases
#define NGRP 8             // barrier tree groups (16 blocks each)
#define NBAR 2
#define SCALE 1099511627776.0  // 2^40 fixed-point scale for exact i64 sums

// bar word-offsets (128B-padded slots)
#define ROOT_SLOT (NBAR * NGRP)              // slots 16,17
#define DONE_OFF  ((NBAR * NGRP + NBAR) * 32)
#define BAR_U32   ((NBAR * NGRP + NBAR + 1) * 32)  // 608 words

// ---- coherent-point accessors (bypass non-coherent per-XCD L2) ----
__device__ __forceinline__ u32 cldu(const u32* p) {
  return __hip_atomic_load(p, __ATOMIC_RELAXED, __HIP_MEMORY_SCOPE_AGENT);
}
__device__ __forceinline__ void cstu(u32* p, u32 v) {
  __hip_atomic_store(p, v, __ATOMIC_RELAXED, __HIP_MEMORY_SCOPE_AGENT);
}
__device__ __forceinline__ u64 cldull(const u64* p) {
  return __hip_atomic_load(p, __ATOMIC_RELAXED, __HIP_MEMORY_SCOPE_AGENT);
}
__device__ __forceinline__ void cstull(u64* p, u64 v) {
  __hip_atomic_store(p, v, __ATOMIC_RELAXED, __HIP_MEMORY_SCOPE_AGENT);
}
__device__ __forceinline__ void cstd(double* p, double v) {
  __hip_atomic_store(p, v, __ATOMIC_RELAXED, __HIP_MEMORY_SCOPE_AGENT);
}
__device__ __forceinline__ double cldd(const double* p) {
  return __hip_atomic_load(p, __ATOMIC_RELAXED, __HIP_MEMORY_SCOPE_AGENT);
}

// uniform value bin: monotone non-decreasing in x => vbin(v) > vbin(x) => v > x
__device__ __forceinline__ int vbin(float x) {
  int b = (int)((x - (float)XMIN) * INVW);
  return b < 0 ? 0 : (b > NBIN - 1 ? NBIN - 1 : b);
}

__device__ __forceinline__ u64 shfl_up_u64(u64 v, int o) {
  u32 lo = (u32)v, hi = (u32)(v >> 32);
  lo = __shfl_up(lo, o);
  hi = __shfl_up(hi, o);
  return ((u64)hi << 32) | lo;
}

// Fenceless device-scope tree barrier (proven r10). All cross-phase data goes
// through coherent-point ops; __syncthreads drains each wave's vmcnt before
// s_barrier, so the block's coherent stores are globally visible before the
// leader's arrival RMW. No __threadfence -> no L2 writeback/invalidate storms.
__device__ __forceinline__ void gbar(u32* bar, int idx) {
  __syncthreads();
  if (threadIdx.x == 0) {
    int g = (int)(blockIdx.x >> 4);  // 8 groups x 16 blocks
    u32 old = __hip_atomic_fetch_add(&bar[(idx * NGRP + g) * 32], 1u,
                                     __ATOMIC_RELAXED, __HIP_MEMORY_SCOPE_AGENT);
    if (old == 15u)
      __hip_atomic_fetch_add(&bar[(ROOT_SLOT + idx) * 32], 1u,
                             __ATOMIC_RELAXED, __HIP_MEMORY_SCOPE_AGENT);
    while (__hip_atomic_load(&bar[(ROOT_SLOT + idx) * 32], __ATOMIC_RELAXED,
                             __HIP_MEMORY_SCOPE_AGENT) < (u32)NGRP)
      __builtin_amdgcn_s_sleep(1);
  }
  __syncthreads();
}

__global__ __launch_bounds__(BS) void k_mega(
    const float* __restrict__ in0, const float* __restrict__ in1,
    u32* gbits, u32* bar, u32* gCnt, u64* gSum,
    double* part, float* out) {
  __shared__ struct {
    union {
      u32 bits[NW];                               // 2 KB  (B, T)
      struct { u32 sc[CAP]; u64 ss[CAP]; } d;     // 12 KB (D hist; E compacted)
    } u;
    u32 h[CAP];                                   // 4 KB  (E counts/prefix; vx)
    u64 hs[CAP];                                  // 8 KB  (E sums -> C; vC)
    float kv[CAP];                                // 4 KB  (E compacted v)
    float tv[2][CAP];                             // 8 KB  thresholds / vertex lv
    double ls[2][CAP];                            // 16 KB vertex slopes
    int its[BS];                                  // 2 KB  scan space
    double s0[BS], s1[BS], s2[BS];                // 12 KB (F)
  } S;  // ~66 KB
  __shared__ int sh_ntop;
  __shared__ int sh_last;
  const int blk = blockIdx.x, t = threadIdx.x;
  const int arr = blk >> 6, b = blk & 63;
  const float* pin = arr ? in1 : in0;

  // input loaded once; reused in phases B and D
  float4 v4 = ((const float4*)(pin + b * EPB))[t];  // 512 x float4 = 2048
  float xs[4] = {v4.x, v4.y, v4.z, v4.w};

  // ---- phase B: bin-occupancy bitmask; also zero the global histogram ----
  S.u.bits[t] = 0u;
  {
    int i = blk * BS + t;
    if (i < 2 * CAP) { cstu(&gCnt[i], 0u); cstull(&gSum[i], 0ull); }
  }
  __syncthreads();
#pragma unroll
  for (int e = 0; e < 4; e++) {
    int bn = vbin(xs[e]);
    atomicOr(&S.u.bits[bn >> 5], 1u << (bn & 31));  // LDS: order-independent
  }
  __syncthreads();
  {
    u32 w = S.u.bits[t];
    if (w) atomicOr(&gbits[arr * NW + t], w);  // coherent RMW merge
  }
  gbar(bar, 0);

  // ---- phase T: derive thresholds from the bitmask (both arrays, redundant,
  // deterministic). A hull vertex's gap > reg spans >=157 bins, so the upper
  // value's bin is preceded by >=1 empty bin: one threshold at the middle of
  // each such empty bin covers every vertex position (elements in bins >= b
  // are > v by > BINW/2 >> float-binning slop; bins <= b-2 are < v; bin b-1
  // empty => #{x > v} = #elems in bins >= b exactly). Specials: v=XMAX+1
  // gives the (0,0) left endpoint; v=XMIN-1 gives p=N. Over-inclusion (1-bin
  // gaps) is discarded by the exact f64 hull. Thresholds come out SORTED
  // descending -- no rank-sort anywhere. ----
  int tcn[2];
  for (int a2 = 0; a2 < 2; a2++) {
    S.u.bits[t] = cldu(&gbits[a2 * NW + t]);  // word t of array a2
    __syncthreads();
    u32 occ = S.u.bits[t];
    u32 carry = (t > 0) ? (S.u.bits[t - 1] >> 31) : 0u;
    u32 emit = occ & ~((occ << 1) | carry);   // occupied bin with empty predecessor
    if (t == 0) emit &= ~1u;                  // bin 0 has no predecessor
    int c = __popc(emit);
    S.its[t] = c;
    __syncthreads();
    for (int off = 1; off < BS; off <<= 1) {
      int v = (t >= off) ? S.its[t - off] : 0;
      __syncthreads();
      S.its[t] += v;
      __syncthreads();
    }
    int m = S.its[BS - 1];
    int base = S.its[t] - c;
    int cn = m + 2; if (cn > CAP) cn = CAP;   // safety clamp (m ~300 << CAP)
    if (t == 0) {
      S.tv[a2][0] = (float)(XMAX + 1.0);      // p = 0 endpoint
      S.tv[a2][cn - 1] = (float)(XMIN - 1.0); // p = N sentinel
    }
    u32 e2 = emit;
    int a = base;
    while (e2) {
      int bit = __ffs((int)e2) - 1;
      e2 &= e2 - 1;
      int bin = t * 32 + bit;
      int idx = m - a;                        // descending placement, 1..m
      if (idx >= 1 && idx <= CAP - 2)
        S.tv[a2][idx] = (float)(XMIN + ((double)bin - 0.5) * BINW);
      a++;
    }
    tcn[a2] = cn;
    __syncthreads();
  }

  // ---- phase D: segment histogram (own array) -> global integer hist ----
  // s(x) = #{v >= x} via binary search over descending thresholds; LDS count
  // (u32) + exact fixed-point sum (i64 llrint(x*2^40)), wave-aggregated;
  // merged with coherent integer atomicAdds (commutative+exact -> determin.).
  {
    int cn = tcn[arr];
    for (int j = t; j < cn; j += BS) { S.u.d.sc[j] = 0u; S.u.d.ss[j] = 0ull; }
    __syncthreads();
    int lane = t & 63;
    for (int e = 0; e < 4; e++) {
      float x = xs[e];
      int lo = 0, hi = cn;
      while (lo < hi) {  // descending: lo = #{v >= x}, in [1, cn-1]
        int mid = (lo + hi) >> 1;
        if (S.tv[arr][mid] >= x) lo = mid + 1; else hi = mid;
      }
      long long q = llrint((double)x * SCALE);
      u64 todo = ~0ull;
      while (todo) {
        int leader = (int)__ffsll(todo) - 1;
        int lo_l = __shfl(lo, leader);
        u64 grp = __ballot(lo == lo_l);
        long long vq = (lo == lo_l) ? q : 0ll;
        int vc = (lo == lo_l) ? 1 : 0;
#pragma unroll
        for (int o = 32; o > 0; o >>= 1) {
          vq += __shfl_xor(vq, o);
          vc += __shfl_xor(vc, o);
        }
        if (lane == leader) {
          atomicAdd(&S.u.d.sc[lo_l], (u32)vc);
          atomicAdd(&S.u.d.ss[lo_l], (u64)vq);
        }
        todo &= ~grp;
      }
    }
    __syncthreads();
    for (int j = t; j < cn; j += BS) {
      u32 c = S.u.d.sc[j];
      if (c) {
        atomicAdd(&gCnt[arr * CAP + j], c);
        atomicAdd(&gSum[arr * CAP + j], S.u.d.ss[j]);
      }
    }
  }
  gbar(bar, 1);

  // ---- phase E (all blocks, redundant): prefix -> (p, C[p]) -> concavity
  // filter -> compact -> serial monotone chain -> vertex lv/ls. Identical
  // integer inputs -> identical results in every block. ----
  int segn[2];
  for (int a2 = 0; a2 < 2; a2++) {
    int cn = tcn[a2];
    for (int j = t; j < cn; j += BS) {
      S.h[j] = cldu(&gCnt[a2 * CAP + j]);
      S.hs[j] = cldull(&gSum[a2 * CAP + j]);
    }
    __syncthreads();
    // wave-0 inclusive prefix (exact integers); count_j = #{x > v_j}
    if (t < 64) {
      int per = (cn + 63) >> 6;
      int beg = t * per, end = beg + per; if (end > cn) end = cn;
      u32 rc = 0; u64 rs = 0;
      for (int j = beg; j < end; j++) {
        rc += S.h[j]; rs += S.hs[j];
        S.h[j] = rc;  S.hs[j] = rs;
      }
      u32 tcv = rc; u64 tsv = rs;
      for (int o = 1; o < 64; o <<= 1) {
        u32 pc = __shfl_up(tcv, o);
        u64 ps = shfl_up_u64(tsv, o);
        if (t >= o) { tcv += pc; tsv += ps; }
      }
      u32 ec = tcv - rc; u64 es = tsv - rs;
      for (int j = beg; j < end; j++) { S.h[j] += ec; S.hs[j] += es; }
    }
    __syncthreads();
    // C[p_j] = S_j/reg - (p*n - p(p-1)/2), in place (exact-in-f64 inputs)
    double* Cv = (double*)S.hs;
    for (int j = t; j < cn; j += BS) {
      double pd = (double)S.h[j];
      double s = (double)(long long)S.hs[j] / SCALE;
      Cv[j] = s / 0.1 - (pd * (double)N_ELEM - pd * (pd - 1.0) * 0.5);
    }
    __syncthreads();
    // local-concavity filter (sound: a point on/below its neighbors' chord is
    // never a majorant vertex -- discrete maximum principle covers runs of
    // simultaneous drops) + dup removal; then order-preserving compaction.
    int kflag[2], cloc = 0;
#pragma unroll
    for (int q = 0; q < 2; q++) {
      int j = 2 * t + q;
      kflag[q] = 0;
      if (j < cn) {
        bool keep;
        if (j == 0) keep = true;
        else if (S.h[j] == S.h[j - 1]) keep = false;        // dup diagram point
        else if (j == cn - 1) keep = true;                  // right endpoint
        else if (S.h[j + 1] <= S.h[j]) keep = true;         // next is dup
        else {
          double dl = (Cv[j] - Cv[j - 1]) * (double)(S.h[j + 1] - S.h[j]);
          double dr = (Cv[j + 1] - Cv[j]) * (double)(S.h[j] - S.h[j - 1]);
          keep = dl > dr;                                   // strictly concave
        }
        kflag[q] = keep ? 1 : 0;
        cloc += kflag[q];
      }
    }
    S.its[t] = cloc;
    __syncthreads();
    for (int off = 1; off < BS; off <<= 1) {
      int v = (t >= off) ? S.its[t - off] : 0;
      __syncthreads();
      S.its[t] += v;
      __syncthreads();
    }
    int kn = S.its[BS - 1];
    int kb = S.its[t] - cloc;
    double* kC = (double*)S.u.d.ss;
    {
      int a = kb;
#pragma unroll
      for (int q = 0; q < 2; q++) {
        int j = 2 * t + q;
        if (j < cn && kflag[q]) {
          S.u.d.sc[a] = S.h[j];
          kC[a] = Cv[j];
          S.kv[a] = S.tv[a2][j];
          a++;
        }
      }
    }
    __syncthreads();
    // serial monotone chain over ~kn<=60 survivors; vertices -> h/Cv/tv[a2]
    if (t == 0) {
      int top = 0, aX = 0, bX = 0;
      double cA = 0.0, cB = 0.0;
      for (int k = 0; k < kn; k++) {
        int i = (int)S.u.d.sc[k];
        double Ci = kC[k];
        float vi = S.kv[k];
        while (top >= 2) {
          double cr = (double)(bX - aX) * (Ci - cA) - (cB - cA) * (double)(i - aX);
          if (cr >= 0.0) {  // bX on/below chord aX->i : pop
            top--;
            bX = aX; cB = cA;
            if (top >= 2) { aX = (int)S.h[top - 2]; cA = Cv[top - 2]; }
          } else break;
        }
        S.h[top] = (u32)i; Cv[top] = Ci; S.tv[a2][top] = vi;
        aX = bX; cA = cB;
        bX = i;  cB = Ci;
        top++;
      }
      sh_ntop = top;
    }
    __syncthreads();
    {
      int top = sh_ntop;
      for (int k = t; k < top - 1; k += BS)
        S.ls[a2][k] = (Cv[k + 1] - Cv[k]) /
                      (double)((int)S.h[k + 1] - (int)S.h[k]);
      segn[a2] = top - 1;
    }
    __syncthreads();
  }

  // ---- phase F: fused rank + centered moments ----
  // x in segment k iff tv[k] >= x > tv[k+1]; rank = x/reg - slope_k. Mean is
  // analytic: permutahedron projection preserves sum -> mean = (N+1)/2.
  {
    int n0 = segn[0], n1 = segn[1];
    const double m = 0.5 * (double)(N_ELEM + 1);  // 65536.5
    double a0 = 0.0, a1 = 0.0, a2v = 0.0;
    float2 x2 = ((const float2*)(in0 + blk * 1024))[t];
    float2 y2 = ((const float2*)(in1 + blk * 1024))[t];
    float xx[2] = {x2.x, x2.y};
    float yy[2] = {y2.x, y2.y};
#pragma unroll
    for (int e = 0; e < 2; e++) {
      float x = xx[e], y = yy[e];
      int k0 = 0, k1 = 0;
      for (int k = 1; k < n0; k++) if (x <= S.tv[0][k]) k0 = k;
      for (int k = 1; k < n1; k++) if (y <= S.tv[1][k]) k1 = k;
      double ra = (double)x / 0.1 - S.ls[0][k0] - m;
      double rb = (double)y / 0.1 - S.ls[1][k1] - m;
      a0 += ra * rb;
      a1 += ra * ra;
      a2v += rb * rb;
    }
    S.s0[t] = a0; S.s1[t] = a1; S.s2[t] = a2v;
    __syncthreads();
    for (int off = BS / 2; off > 0; off >>= 1) {
      if (t < off) {
        S.s0[t] += S.s0[t + off];
        S.s1[t] += S.s1[t + off];
        S.s2[t] += S.s2[t + off];
      }
      __syncthreads();
    }
    if (t == 0) {
      cstd(&part[blk], S.s0[0]);
      cstd(&part[GRID + blk], S.s1[0]);
      cstd(&part[2 * GRID + blk], S.s2[0]);
    }
  }

  // ---- phase G: last-block-out final reduction ----
  __syncthreads();  // drains t0's part stores (vmcnt waited before s_barrier)
  if (t == 0) {
    u32 old = __hip_atomic_fetch_add(&bar[DONE_OFF], 1u,
                                     __ATOMIC_RELAXED, __HIP_MEMORY_SCOPE_AGENT);
    sh_last = (old == (u32)(GRID - 1)) ? 1 : 0;
  }
  __syncthreads();
  if (sh_last && t < 64) {
    double v0 = 0.0, v1 = 0.0, v2 = 0.0;
    for (int k = t; k < GRID; k += 64) {  // fixed order -> deterministic
      v0 += cldd(&part[k]);
      v1 += cldd(&part[GRID + k]);
      v2 += cldd(&part[2 * GRID + k]);
    }
#pragma unroll
    for (int off = 32; off > 0; off >>= 1) {
      v0 += __shfl_down(v0, off);
      v1 += __shfl_down(v1, off);
      v2 += __shfl_down(v2, off);
    }
    if (t == 0) out[0] = (float)(v0 / (sqrt(v1) * sqrt(v2)));
  }
}

// ---------------- host ----------------
extern "C" void kernel_launch(void* const* d_in, const int* in_sizes, int n_in,
                              void* d_out, int out_size, void* d_ws, size_t ws_size,
                              hipStream_t stream) {
  const float* in0 = (const float*)d_in[0];
  const float* in1 = (const float*)d_in[1];
  float* out = (float*)d_out;

  size_t off = 0;
  char* base = (char*)d_ws;
  auto alloc = [&](size_t bytes) -> char* {
    char* p = base + off;
    off += (bytes + 63) & ~(size_t)63;
    return p;
  };
  // gbits + bar contiguous -> one memset covers both
  u32* gbits = (u32*)alloc(sizeof(u32) * 2 * NW);   // 4096 B (64-aligned)
  u32* bar   = (u32*)alloc(sizeof(u32) * BAR_U32);  // 2432 B
  u32* gCnt  = (u32*)alloc(sizeof(u32) * 2 * CAP);
  u64* gSum  = (u64*)alloc(sizeof(u64) * 2 * CAP);
  double* part = (double*)alloc(sizeof(double) * 3 * GRID);
  (void)ws_size; (void)in_sizes; (void)n_in; (void)out_size;

  // single init memset: occupancy bitmask + barrier tree + done counter
  // (replayed in the graph every iteration -> stateless)
  hipMemsetAsync(gbits, 0, sizeof(u32) * (2 * NW + BAR_U32), stream);

  k_mega<<<dim3(GRID), dim3(BS), 0, stream>>>(
      in0, in1, gbits, bar, gCnt, gSum, part, out);
}

// Round 16
// 33.547 us; speedup vs baseline: 1.4615x; 1.4615x over previous
//
#include <hip/hip_runtime.h>
#include <math.h>

typedef unsigned int u32;
typedef unsigned long long u64;

#define N_ELEM 131072
#define NBIN 16384         // uniform VALUE bins over [-4.2, 4.2]
#define NW (NBIN / 32)     // occupancy bitmask words (512)
#define XMIN (-4.2)
#define BINW (8.4 / 16384.0)        // 5.127e-4
#define INVW ((float)(16384.0 / 8.4))
#define DPROOF 190         // proof range in bins: 191*BINW = 0.0979 < GMARG
#define CAP 1024           // candidate capacity per array (typ. ~300 used)
#define GMARG 0.0999       // conservative gap margin (< 0.1*(1-1e-9))
#define GRID 128           // persistent blocks (<= 256 CUs -> co-resident)
#define BS 512             // threads per block (8 waves)
#define EPB 2048           // elements per block in data phases
#define NGRP 8             // barrier tree groups (16 blocks each)
#define NBAR 3
#define SCALE 1099511627776.0  // 2^40 fixed-point scale for exact i64 sums

// bar word-offsets (128B-padded slots)
#define ROOT_SLOT (NBAR * NGRP)                    // slots 24..26
#define CC_OFF    ((NBAR * NGRP + NBAR) * 32)      // candCnt[arr*32]
#define DONE_OFF  ((NBAR * NGRP + NBAR + 2) * 32)
#define BAR_U32   ((NBAR * NGRP + NBAR + 3) * 32)  // 960 words

// ---- coherent-point accessors (bypass non-coherent per-XCD L2) ----
__device__ __forceinline__ u32 cldu(const u32* p) {
  return __hip_atomic_load(p, __ATOMIC_RELAXED, __HIP_MEMORY_SCOPE_AGENT);
}
__device__ __forceinline__ void cstu(u32* p, u32 v) {
  __hip_atomic_store(p, v, __ATOMIC_RELAXED, __HIP_MEMORY_SCOPE_AGENT);
}
__device__ __forceinline__ u64 cldull(const u64* p) {
  return __hip_atomic_load(p, __ATOMIC_RELAXED, __HIP_MEMORY_SCOPE_AGENT);
}
__device__ __forceinline__ void cstull(u64* p, u64 v) {
  __hip_atomic_store(p, v, __ATOMIC_RELAXED, __HIP_MEMORY_SCOPE_AGENT);
}
__device__ __forceinline__ float cldf(const float* p) {
  return __hip_atomic_load(p, __ATOMIC_RELAXED, __HIP_MEMORY_SCOPE_AGENT);
}
__device__ __forceinline__ void cstf(float* p, float v) {
  __hip_atomic_store(p, v, __ATOMIC_RELAXED, __HIP_MEMORY_SCOPE_AGENT);
}
__device__ __forceinline__ void cstd(double* p, double v) {
  __hip_atomic_store(p, v, __ATOMIC_RELAXED, __HIP_MEMORY_SCOPE_AGENT);
}
__device__ __forceinline__ double cldd(const double* p) {
  return __hip_atomic_load(p, __ATOMIC_RELAXED, __HIP_MEMORY_SCOPE_AGENT);
}

// uniform value bin: monotone non-decreasing in x => vbin(v) > vbin(x) => v > x
__device__ __forceinline__ int vbin(float x) {
  int b = (int)((x - (float)XMIN) * INVW);
  return b < 0 ? 0 : (b > NBIN - 1 ? NBIN - 1 : b);
}

__device__ __forceinline__ u64 shfl_up_u64(u64 v, int o) {
  u32 lo = (u32)v, hi = (u32)(v >> 32);
  lo = __shfl_up(lo, o);
  hi = __shfl_up(hi, o);
  return ((u64)hi << 32) | lo;
}

// Fenceless device-scope tree barrier (proven r10). All cross-phase data goes
// through coherent-point ops; __syncthreads drains each wave's vmcnt before
// s_barrier, so the block's coherent stores are globally visible before the
// leader's arrival RMW. No __threadfence -> no L2 writeback/invalidate storms.
__device__ __forceinline__ void gbar(u32* bar, int idx) {
  __syncthreads();
  if (threadIdx.x == 0) {
    int g = (int)(blockIdx.x >> 4);  // 8 groups x 16 blocks
    u32 old = __hip_atomic_fetch_add(&bar[(idx * NGRP + g) * 32], 1u,
                                     __ATOMIC_RELAXED, __HIP_MEMORY_SCOPE_AGENT);
    if (old == 15u)
      __hip_atomic_fetch_add(&bar[(ROOT_SLOT + idx) * 32], 1u,
                             __ATOMIC_RELAXED, __HIP_MEMORY_SCOPE_AGENT);
    while (__hip_atomic_load(&bar[(ROOT_SLOT + idx) * 32], __ATOMIC_RELAXED,
                             __HIP_MEMORY_SCOPE_AGENT) < (u32)NGRP)
      __builtin_amdgcn_s_sleep(1);
  }
  __syncthreads();
}

__global__ __launch_bounds__(BS) void k_mega(
    const float* __restrict__ in0, const float* __restrict__ in1,
    u32* gbits, u32* bar, float* candVal, u32* gCnt, u64* gSum,
    double* part, float* out) {
  __shared__ struct {
    union {
      u32 bits[NW];                               // 2 KB  (B, C)
      struct { u32 sc[CAP]; u64 ss[CAP]; } d;     // 12 KB (D hist; E compacted)
      float raw[CAP];                             // 4 KB  (sort scratch)
    } u;
    u32 h[CAP];                                   // 4 KB  counts/prefix; stack p
    u64 hs[CAP];                                  // 8 KB  sums -> C; stack C
    float kv[CAP];                                // 4 KB  compacted thresholds
    float lv[2][CAP];                             // 8 KB  sorted thr -> vertex lv
    double ls[2][CAP];                            // 16 KB vertex slopes
    int wtot[8];                                  // wave totals for compaction
    double s0[BS], s1[BS], s2[BS];                // 12 KB (F)
  } S;  // ~64 KB
  __shared__ int sh_ntop;
  __shared__ int sh_last;
  const int blk = blockIdx.x, t = threadIdx.x;
  const int arr = blk >> 6, b = blk & 63;
  const float* pin = arr ? in1 : in0;
  u32* candCnt = bar + CC_OFF;  // candCnt[arr*32]

  // load once; reused across phases B, C, D
  float4 v4 = ((const float4*)(pin + b * EPB))[t];  // 512 x float4 = 2048
  float xs[4] = {v4.x, v4.y, v4.z, v4.w};

  // ---- phase B: bin-occupancy bitmask (LDS-local, OR-merge to global);
  // also zero the global integer histogram (first used after bar 1). ----
  for (int k = t; k < NW; k += BS) S.u.bits[k] = 0u;
  {
    int i = blk * BS + t;
    if (i < 2 * CAP) { cstu(&gCnt[i], 0u); cstull(&gSum[i], 0ull); }
  }
  __syncthreads();
#pragma unroll
  for (int e = 0; e < 4; e++) {
    int bn = vbin(xs[e]);
    atomicOr(&S.u.bits[bn >> 5], 1u << (bn & 31));  // LDS: order-independent
  }
  __syncthreads();
  {
    u32* gb = gbits + arr * NW;
    for (int k = t; k < NW; k += BS) {
      u32 w = S.u.bits[k];
      if (w) atomicOr(&gb[k], w);  // coherent RMW merge, nonzero words only
    }
  }
  gbar(bar, 0);

  // ---- phase C: candidate detection via occupancy bitmask ----
  // Flag x unless PROVEN non-vertex: any occupied bin b' in (b, b+DPROOF],
  // b' <= NBIN-2, holds v with v > x (monotone vbin) and v <= x + 191*BINW
  // = x+0.0979 < x+GMARG. Then the sorted gap above x's run is < reg -> x
  // cannot be a hull vertex (vertex at p => y_{p-1} > y_p => gap > reg).
  // Over-inclusion safe: flagged v yields a valid diagram point; the exact
  // f64 hull (phase E) discards non-vertices.
  {
    const u32* gb = gbits + arr * NW;
    for (int k = t; k < NW; k += BS) S.u.bits[k] = cldu(&gb[k]);
    __syncthreads();
    if ((blk == 0 || blk == 64) && t == 0) {  // right-endpoint sentinel: p = N
      u32 s = atomicAdd(&candCnt[arr * 32], 1u);
      if (s < CAP) cstf(&candVal[arr * CAP + s], -INFINITY);
    }
    for (int e = 0; e < 4; e++) {
      float x = xs[e];
      int bn = vbin(x);
      int lim = bn + DPROOF;
      if (lim > NBIN - 2) lim = NBIN - 2;
      bool proven = false;
      if (lim > bn) {
        int w0 = bn >> 5, w1 = lim >> 5;
        u32 m0 = S.u.bits[w0] & ~((2u << (bn & 31)) - 1u);  // bits strictly above bn
        if (w0 == w1) {
          proven = (m0 & ((2u << (lim & 31)) - 1u)) != 0u;
        } else if (m0) {
          proven = true;
        } else {
          for (int w = w0 + 1; w < w1 && !proven; w++) proven = (S.u.bits[w] != 0u);
          if (!proven) proven = (S.u.bits[w1] & ((2u << (lim & 31)) - 1u)) != 0u;
        }
      }
      if (!proven) {
        u32 s = atomicAdd(&candCnt[arr * 32], 1u);
        if (s < CAP) cstf(&candVal[arr * CAP + s], x);
      }
    }
  }
  gbar(bar, 1);

  // ---- phase D: LDS segment histogram -> global integer hist ----
  // Thresholds sorted descending into lv[arr] (deterministic: equal values
  // give identical sorted content). s(x) = #{v >= x} via binary search;
  // LDS count (u32) + exact fixed-point sum (i64 llrint(x*2^40)), wave-
  // aggregated; then <= cnt atomicAdds/block merge into gCnt/gSum (integer
  // adds: commutative+exact -> deterministic; per-address contention <= 128).
  {
    u32 cc = cldu(&candCnt[arr * 32]);
    int cn = (int)(cc < (u32)CAP ? cc : (u32)CAP);
    for (int j = t; j < cn; j += BS) S.u.raw[j] = cldf(&candVal[arr * CAP + j]);
    __syncthreads();
    for (int j = t; j < cn; j += BS) {
      float vj = S.u.raw[j];
      int rk = 0;
      for (int k = 0; k < cn; k++) {
        float vk = S.u.raw[k];
        rk += (vk > vj) || (vk == vj && k < j);
      }
      S.lv[arr][rk] = vj;
    }
    __syncthreads();
    for (int j = t; j < cn; j += BS) { S.u.d.sc[j] = 0u; S.u.d.ss[j] = 0ull; }
    __syncthreads();
    int lane = t & 63;
    for (int e = 0; e < 4; e++) {
      float x = xs[e];
      int lo = 0, hi = cn;
      while (lo < hi) {  // descending array: lo = #{v >= x}
        int mid = (lo + hi) >> 1;
        if (S.lv[arr][mid] >= x) lo = mid + 1; else hi = mid;
      }
      long long q = llrint((double)x * SCALE);
      u64 todo = ~0ull;  // full wave active
      while (todo) {
        int leader = (int)__ffsll(todo) - 1;
        int lo_l = __shfl(lo, leader);
        u64 grp = __ballot(lo == lo_l);
        long long vq = (lo == lo_l) ? q : 0ll;
        int vc = (lo == lo_l) ? 1 : 0;
#pragma unroll
        for (int o = 32; o > 0; o >>= 1) {
          vq += __shfl_xor(vq, o);
          vc += __shfl_xor(vc, o);
        }
        if (lane == leader) {
          atomicAdd(&S.u.d.sc[lo_l], (u32)vc);
          atomicAdd(&S.u.d.ss[lo_l], (u64)vq);
        }
        todo &= ~grp;
      }
    }
    __syncthreads();
    for (int j = t; j < cn; j += BS) {
      u32 c = S.u.d.sc[j];
      if (c) {  // device-scope (coherent) integer adds
        atomicAdd(&gCnt[arr * CAP + j], c);
        atomicAdd(&gSum[arr * CAP + j], S.u.d.ss[j]);
      }
    }
  }
  gbar(bar, 2);

  // ---- phase E (ALL blocks, redundant -> no extra barrier): prefix of hist
  // -> (p, C[p]) -> local-concavity filter -> wave-scan compaction -> short
  // serial monotone chain -> vertex lv/ls. Identical integers in -> identical
  // results in every block. Filter soundness: a point on/below its immediate
  // neighbors' chord is covered by the majorant without it -> never a vertex.
  int segn[2];
  for (int a2 = 0; a2 < 2; a2++) {
    u32 cc = cldu(&candCnt[a2 * 32]);
    int cn = (int)(cc < (u32)CAP ? cc : (u32)CAP);
    if (a2 != arr) {  // rebuild sorted thresholds for the other array
      for (int j = t; j < cn; j += BS) S.u.raw[j] = cldf(&candVal[a2 * CAP + j]);
      __syncthreads();
      for (int j = t; j < cn; j += BS) {
        float vj = S.u.raw[j];
        int rk = 0;
        for (int k = 0; k < cn; k++) {
          float vk = S.u.raw[k];
          rk += (vk > vj) || (vk == vj && k < j);
        }
        S.lv[a2][rk] = vj;
      }
    }
    __syncthreads();
    for (int j = t; j < cn; j += BS) {
      S.h[j] = cldu(&gCnt[a2 * CAP + j]);
      S.hs[j] = cldull(&gSum[a2 * CAP + j]);
    }
    __syncthreads();
    // wave-0 inclusive prefix (exact integers); count_j = #{x > v_j}
    if (t < 64) {
      int per = (cn + 63) >> 6;
      int beg = t * per, end = beg + per; if (end > cn) end = cn;
      u32 rc = 0; u64 rs = 0;
      for (int j = beg; j < end; j++) {
        rc += S.h[j]; rs += S.hs[j];
        S.h[j] = rc;  S.hs[j] = rs;
      }
      u32 tcv = rc; u64 tsv = rs;
      for (int o = 1; o < 64; o <<= 1) {
        u32 pc = __shfl_up(tcv, o);
        u64 ps = shfl_up_u64(tsv, o);
        if (t >= o) { tcv += pc; tsv += ps; }
      }
      u32 ec = tcv - rc; u64 es = tsv - rs;
      for (int j = beg; j < end; j++) { S.h[j] += ec; S.hs[j] += es; }
    }
    __syncthreads();
    // C[p_j] = S_j/reg - (p*n - p(p-1)/2), in place (exact-in-f64 inputs)
    double* Cv = (double*)S.hs;
    for (int j = t; j < cn; j += BS) {
      double pd = (double)S.h[j];
      double s = (double)(long long)S.hs[j] / SCALE;
      Cv[j] = s / 0.1 - (pd * (double)N_ELEM - pd * (pd - 1.0) * 0.5);
    }
    __syncthreads();
    // concavity filter (2 items/thread) + dup removal
    int kflag[2], cloc = 0;
#pragma unroll
    for (int q = 0; q < 2; q++) {
      int j = 2 * t + q;
      kflag[q] = 0;
      if (j < cn) {
        bool keep;
        if (j == 0) keep = true;
        else if (S.h[j] == S.h[j - 1]) keep = false;        // dup diagram point
        else if (j == cn - 1) keep = true;                  // right endpoint
        else if (S.h[j + 1] <= S.h[j]) keep = true;         // next is dup
        else {
          double dl = (Cv[j] - Cv[j - 1]) * (double)(S.h[j + 1] - S.h[j]);
          double dr = (Cv[j + 1] - Cv[j]) * (double)(S.h[j] - S.h[j - 1]);
          keep = dl > dr;                                   // strictly concave
        }
        kflag[q] = keep ? 1 : 0;
        cloc += kflag[q];
      }
    }
    // wave-shuffle compaction scan (2 __syncthreads total, no Hillis-Steele)
    {
      int lane = t & 63, w = t >> 6;
      int v = cloc;
      for (int o = 1; o < 64; o <<= 1) {
        int p = __shfl_up(v, o);
        if (lane >= o) v += p;
      }
      if (lane == 63) S.wtot[w] = v;
      __syncthreads();
      int woff = 0, kn = 0;
#pragma unroll
      for (int i = 0; i < 8; i++) {
        int wv = S.wtot[i];
        kn += wv;
        if (i < w) woff += wv;
      }
      int a = woff + v - cloc;  // exclusive offset
      u32* kx = S.u.d.sc;
      double* kC = (double*)S.u.d.ss;
#pragma unroll
      for (int q = 0; q < 2; q++) {
        int j = 2 * t + q;
        if (j < cn && kflag[q]) {
          kx[a] = S.h[j];
          kC[a] = Cv[j];
          S.kv[a] = S.lv[a2][j];
          a++;
        }
      }
      __syncthreads();
      // serial monotone chain over ~kn<=80 survivors; stack -> h/Cv/lv[a2]
      if (t == 0) {
        int top = 0, aX = 0, bX = 0, prevP = -1;
        double cA = 0.0, cB = 0.0;
        for (int k = 0; k < kn; k++) {
          int i = (int)kx[k];
          if (i == prevP) continue;
          prevP = i;
          double Ci = kC[k];
          float vi = S.kv[k];
          while (top >= 2) {
            double cr = (double)(bX - aX) * (Ci - cA) - (cB - cA) * (double)(i - aX);
            if (cr >= 0.0) {  // bX on/below chord aX->i : pop
              top--;
              bX = aX; cB = cA;
              if (top >= 2) { aX = (int)S.h[top - 2]; cA = Cv[top - 2]; }
            } else break;
          }
          S.h[top] = (u32)i; Cv[top] = Ci; S.lv[a2][top] = vi;
          aX = bX; cA = cB;
          bX = i;  cB = Ci;
          top++;
        }
        sh_ntop = top;
      }
    }
    __syncthreads();
    {
      int top = sh_ntop;
      for (int k = t; k < top - 1; k += BS)
        S.ls[a2][k] = (Cv[k + 1] - Cv[k]) /
                      (double)((int)S.h[k + 1] - (int)S.h[k]);
      segn[a2] = top - 1;
    }
    __syncthreads();
  }

  // ---- phase F: fused rank + centered moments ----
  // x in segment k iff lv[k] >= x > lv[k+1]; rank = x/reg - slope_k. Mean is
  // analytic: permutahedron projection preserves sum -> mean = (N+1)/2.
  {
    int n0 = segn[0], n1 = segn[1];
    const double m = 0.5 * (double)(N_ELEM + 1);  // 65536.5
    double a0 = 0.0, a1 = 0.0, a2v = 0.0;
    float2 x2 = ((const float2*)(in0 + blk * 1024))[t];
    float2 y2 = ((const float2*)(in1 + blk * 1024))[t];
    float xx[2] = {x2.x, x2.y};
    float yy[2] = {y2.x, y2.y};
#pragma unroll
    for (int e = 0; e < 2; e++) {
      float x = xx[e], y = yy[e];
      int k0 = 0, k1 = 0;
      for (int k = 1; k < n0; k++) if (x <= S.lv[0][k]) k0 = k;
      for (int k = 1; k < n1; k++) if (y <= S.lv[1][k]) k1 = k;
      double ra = (double)x / 0.1 - S.ls[0][k0] - m;
      double rb = (double)y / 0.1 - S.ls[1][k1] - m;
      a0 += ra * rb;
      a1 += ra * ra;
      a2v += rb * rb;
    }
    S.s0[t] = a0; S.s1[t] = a1; S.s2[t] = a2v;
    __syncthreads();
    for (int off = BS / 2; off > 0; off >>= 1) {
      if (t < off) {
        S.s0[t] += S.s0[t + off];
        S.s1[t] += S.s1[t + off];
        S.s2[t] += S.s2[t + off];
      }
      __syncthreads();
    }
    if (t == 0) {
      cstd(&part[blk], S.s0[0]);
      cstd(&part[GRID + blk], S.s1[0]);
      cstd(&part[2 * GRID + blk], S.s2[0]);
    }
  }

  // ---- phase G: last-block-out final reduction ----
  __syncthreads();  // drains t0's part stores (vmcnt waited before s_barrier)
  if (t == 0) {
    u32 old = __hip_atomic_fetch_add(&bar[DONE_OFF], 1u,
                                     __ATOMIC_RELAXED, __HIP_MEMORY_SCOPE_AGENT);
    sh_last = (old == (u32)(GRID - 1)) ? 1 : 0;
  }
  __syncthreads();
  if (sh_last && t < 64) {
    double v0 = 0.0, v1 = 0.0, v2 = 0.0;
    for (int k = t; k < GRID; k += 64) {  // fixed order -> deterministic
      v0 += cldd(&part[k]);
      v1 += cldd(&part[GRID + k]);
      v2 += cldd(&part[2 * GRID + k]);
    }
#pragma unroll
    for (int off = 32; off > 0; off >>= 1) {
      v0 += __shfl_down(v0, off);
      v1 += __shfl_down(v1, off);
      v2 += __shfl_down(v2, off);
    }
    if (t == 0) out[0] = (float)(v0 / (sqrt(v1) * sqrt(v2)));
  }
}

// ---------------- host ----------------
extern "C" void kernel_launch(void* const* d_in, const int* in_sizes, int n_in,
                              void* d_out, int out_size, void* d_ws, size_t ws_size,
                              hipStream_t stream) {
  const float* in0 = (const float*)d_in[0];
  const float* in1 = (const float*)d_in[1];
  float* out = (float*)d_out;

  size_t off = 0;
  char* base = (char*)d_ws;
  auto alloc = [&](size_t bytes) -> char* {
    char* p = base + off;
    off += (bytes + 63) & ~(size_t)63;
    return p;
  };
  // gbits + bar contiguous -> one memset covers both
  u32* gbits   = (u32*)alloc(sizeof(u32) * 2 * NW);       // 4096 B (64-aligned)
  u32* bar     = (u32*)alloc(sizeof(u32) * BAR_U32);      // 3840 B
  float* candVal = (float*)alloc(sizeof(float) * 2 * CAP);
  u32* gCnt    = (u32*)alloc(sizeof(u32) * 2 * CAP);
  u64* gSum    = (u64*)alloc(sizeof(u64) * 2 * CAP);
  double* part = (double*)alloc(sizeof(double) * 3 * GRID);
  (void)ws_size; (void)in_sizes; (void)n_in; (void)out_size;

  // single init memset: occupancy bitmask + barrier tree + counters
  // (replayed in the graph every iteration -> stateless)
  hipMemsetAsync(gbits, 0, sizeof(u32) * (2 * NW + BAR_U32), stream);

  k_mega<<<dim3(GRID), dim3(BS), 0, stream>>>(
      in0, in1, gbits, bar, candVal, gCnt, gSum, part, out);
}

// Round 17
// 30.936 us; speedup vs baseline: 1.5849x; 1.0844x over previous
//
#include <hip/hip_runtime.h>
#include <math.h>

typedef unsigned int u32;
typedef unsigned long long u64;

#define N_ELEM 131072
#define NBIN 16384         // uniform VALUE bins over [-5.5, 5.5]
#define NW (NBIN / 32)     // occupancy words (512) == BS? no, BS=512, NW=512
#define XMIN (-5.5)
#define XSPAN 11.0
#define BINW (11.0 / 16384.0)       // 6.714e-4; gap 0.1 spans >= 147 empty bins
#define INVW ((float)(16384.0 / 11.0))
#define KRUN 140           // emit threshold iff empty run before bin >= KRUN
#define CAP 256            // thresholds per array: <= NBIN/(KRUN+1)+2 = 118
#define GRID 128           // persistent blocks (<= 256 CUs -> co-resident)
#define BS 512             // threads per block (8 waves)
#define EPB 2048           // elements per block in data phases
#define NGRP 8             // barrier tree groups (16 blocks each)
#define NBAR 2
#define SCALE 1099511627776.0  // 2^40 fixed-point scale for exact i64 sums

// bar word-offsets (128B-padded slots)
#define ROOT_SLOT (NBAR * NGRP)                    // slots 16,17
#define DONE_OFF  ((NBAR * NGRP + NBAR) * 32)
#define BAR_U32   ((NBAR * NGRP + NBAR + 1) * 32)  // 608 words

// ---- coherent-point accessors (bypass non-coherent per-XCD L2) ----
__device__ __forceinline__ u32 cldu(const u32* p) {
  return __hip_atomic_load(p, __ATOMIC_RELAXED, __HIP_MEMORY_SCOPE_AGENT);
}
__device__ __forceinline__ void cstu(u32* p, u32 v) {
  __hip_atomic_store(p, v, __ATOMIC_RELAXED, __HIP_MEMORY_SCOPE_AGENT);
}
__device__ __forceinline__ u64 cldull(const u64* p) {
  return __hip_atomic_load(p, __ATOMIC_RELAXED, __HIP_MEMORY_SCOPE_AGENT);
}
__device__ __forceinline__ void cstull(u64* p, u64 v) {
  __hip_atomic_store(p, v, __ATOMIC_RELAXED, __HIP_MEMORY_SCOPE_AGENT);
}
__device__ __forceinline__ void cstd(double* p, double v) {
  __hip_atomic_store(p, v, __ATOMIC_RELAXED, __HIP_MEMORY_SCOPE_AGENT);
}
__device__ __forceinline__ double cldd(const double* p) {
  return __hip_atomic_load(p, __ATOMIC_RELAXED, __HIP_MEMORY_SCOPE_AGENT);
}

// uniform value bin: monotone non-decreasing in x => vbin(v) > vbin(x) => v > x
__device__ __forceinline__ int vbin(float x) {
  int b = (int)((x - (float)XMIN) * INVW);
  return b < 0 ? 0 : (b > NBIN - 1 ? NBIN - 1 : b);
}

__device__ __forceinline__ u64 shfl_up_u64(u64 v, int o) {
  u32 lo = (u32)v, hi = (u32)(v >> 32);
  lo = __shfl_up(lo, o);
  hi = __shfl_up(hi, o);
  return ((u64)hi << 32) | lo;
}

// Fenceless device-scope tree barrier (proven r10). All cross-phase data goes
// through coherent-point ops; __syncthreads drains each wave's vmcnt before
// s_barrier, so the block's coherent stores are globally visible before the
// leader's arrival RMW. No __threadfence -> no L2 writeback/invalidate storms.
__device__ __forceinline__ void gbar(u32* bar, int idx) {
  __syncthreads();
  if (threadIdx.x == 0) {
    int g = (int)(blockIdx.x >> 4);  // 8 groups x 16 blocks
    u32 old = __hip_atomic_fetch_add(&bar[(idx * NGRP + g) * 32], 1u,
                                     __ATOMIC_RELAXED, __HIP_MEMORY_SCOPE_AGENT);
    if (old == 15u)
      __hip_atomic_fetch_add(&bar[(ROOT_SLOT + idx) * 32], 1u,
                             __ATOMIC_RELAXED, __HIP_MEMORY_SCOPE_AGENT);
    while (__hip_atomic_load(&bar[(ROOT_SLOT + idx) * 32], __ATOMIC_RELAXED,
                             __HIP_MEMORY_SCOPE_AGENT) < (u32)NGRP)
      __builtin_amdgcn_s_sleep(1);
  }
  __syncthreads();
}

__global__ __launch_bounds__(BS) void k_mega(
    const float* __restrict__ in0, const float* __restrict__ in1,
    u32* gbits, u32* bar, u32* gCnt, u64* gSum,
    double* part, float* out) {
  __shared__ struct {
    union {
      u32 bits[NW];                               // 2 KB (B, T)
      struct { u32 sc[CAP]; u64 ss[CAP]; } d;     // 3 KB (D hist)
    } u;
    u32 h[CAP];                                   // 1 KB counts/prefix; stack p
    u64 hs[CAP];                                  // 2 KB sums -> C; stack C
    float lv[2][CAP];                             // 2 KB thresholds -> vertex lv
    double ls[2][CAP];                            // 4 KB vertex slopes
    int wtot[8];                                  // wave totals (scan combine)
    double s0[BS], s1[BS], s2[BS];                // 12 KB (F)
  } S;  // ~26 KB
  __shared__ int sh_ntop;
  __shared__ int sh_last;
  const int blk = blockIdx.x, t = threadIdx.x;
  const int arr = blk >> 6, b = blk & 63;
  const float* pin = arr ? in1 : in0;

  // input loaded once; reused in phases B and D
  float4 v4 = ((const float4*)(pin + b * EPB))[t];  // 512 x float4 = 2048
  float xs[4] = {v4.x, v4.y, v4.z, v4.w};

  // ---- phase B: bin-occupancy bitmask (LDS-local, OR-merge to global);
  // also zero the global integer histogram (first used after bar 0). ----
  S.u.bits[t] = 0u;
  {
    int i = blk * BS + t;
    if (i < 2 * CAP) { cstu(&gCnt[i], 0u); cstull(&gSum[i], 0ull); }
  }
  __syncthreads();
#pragma unroll
  for (int e = 0; e < 4; e++) {
    int bn = vbin(xs[e]);
    atomicOr(&S.u.bits[bn >> 5], 1u << (bn & 31));  // LDS: order-independent
  }
  __syncthreads();
  {
    u32 w = S.u.bits[t];
    if (w) atomicOr(&gbits[arr * NW + t], w);  // coherent RMW merge
  }
  gbar(bar, 0);

  // ---- phase T: thresholds from the bitmask (both arrays, redundant,
  // deterministic; no candidate list, no sort). A hull vertex's gap > reg
  // = 0.1 spans >= 147 empty bins, so its upper value's bin is preceded by
  // a >= 147-bin empty run. Emit one threshold (mid of the empty bin just
  // below) for each occupied bin with empty-run >= KRUN=140: every vertex
  // covered; <= NBIN/(KRUN+1)+2 = 118 thresholds by construction. Only the
  // LOWEST set bit of a word can qualify (in-word gap <= 30 < KRUN), and
  // only if the 5 words below are empty far enough. Exactness: threshold
  // v = XMIN+(bin-0.5)*BINW has no element within BINW/2 (run empty), so
  // #{x > v} = #elems in bins >= bin, exact, float-slop-immune. ----
  int tcn[2];
  for (int a2 = 0; a2 < 2; a2++) {
    S.u.bits[t] = cldu(&gbits[a2 * NW + t]);
    __syncthreads();
    u32 wt = S.u.bits[t];
    int flag = 0;
    float tval = 0.f;
    if (wt) {
      int b0 = __ffs((int)wt) - 1;
      int bin = 32 * t + b0;
      int prev = -1000000;  // none found -> emit (conservative at boundary)
      for (int k2 = 1; k2 <= 5; k2++) {
        int w = t - k2;
        if (w < 0) break;
        u32 xw = S.u.bits[w];
        if (xw) { prev = 32 * w + (31 - __clz(xw)); break; }
      }
      // beyond 5 words: prev <= 32t-161 -> gap >= 160 >= KRUN -> emit
      if (bin - prev - 1 >= KRUN) {
        flag = 1;
        tval = (float)(XMIN + ((double)bin - 0.5) * BINW);
      }
    }
    // wave-shuffle compaction scan (2 __syncthreads total)
    int lane = t & 63, w = t >> 6;
    int v = flag;
    for (int o = 1; o < 64; o <<= 1) {
      int p = __shfl_up(v, o);
      if (lane >= o) v += p;
    }
    if (lane == 63) S.wtot[w] = v;
    __syncthreads();
    int woff = 0, m = 0;
#pragma unroll
    for (int i2 = 0; i2 < 8; i2++) {
      int wv = S.wtot[i2];
      m += wv;
      if (i2 < w) woff += wv;
    }
    int a = woff + v - flag;  // ascending rank among emits
    int cn = m + 2; if (cn > CAP) cn = CAP;  // defensive (m <= 118 guaranteed)
    if (flag) {
      int idx = m - a;  // descending placement, 1..m
      if (idx >= 1 && idx <= CAP - 2) S.lv[a2][idx] = tval;
    }
    if (t == 0) {
      S.lv[a2][0] = (float)(XMIN + XSPAN + 1.0);  // p = 0 left endpoint
      S.lv[a2][cn - 1] = (float)(XMIN - 1.0);     // p = N sentinel
    }
    tcn[a2] = cn;
    __syncthreads();
  }

  // ---- phase D: segment histogram (own array) -> global integer hist ----
  // s(x) = #{v >= x} via binary search over descending thresholds; LDS count
  // (u32) + exact fixed-point sum (i64 llrint(x*2^40)), wave-aggregated;
  // merged with coherent integer atomicAdds (commutative+exact -> determin.).
  {
    int cn = tcn[arr];
    for (int j = t; j < cn; j += BS) { S.u.d.sc[j] = 0u; S.u.d.ss[j] = 0ull; }
    __syncthreads();
    int lane = t & 63;
    for (int e = 0; e < 4; e++) {
      float x = xs[e];
      int lo = 0, hi = cn;
      while (lo < hi) {  // descending: lo = #{v >= x}, in [1, cn-1]
        int mid = (lo + hi) >> 1;
        if (S.lv[arr][mid] >= x) lo = mid + 1; else hi = mid;
      }
      long long q = llrint((double)x * SCALE);
      u64 todo = ~0ull;
      while (todo) {
        int leader = (int)__ffsll(todo) - 1;
        int lo_l = __shfl(lo, leader);
        u64 grp = __ballot(lo == lo_l);
        long long vq = (lo == lo_l) ? q : 0ll;
        int vc = (lo == lo_l) ? 1 : 0;
#pragma unroll
        for (int o = 32; o > 0; o >>= 1) {
          vq += __shfl_xor(vq, o);
          vc += __shfl_xor(vc, o);
        }
        if (lane == leader) {
          atomicAdd(&S.u.d.sc[lo_l], (u32)vc);
          atomicAdd(&S.u.d.ss[lo_l], (u64)vq);
        }
        todo &= ~grp;
      }
    }
    __syncthreads();
    for (int j = t; j < cn; j += BS) {
      u32 c = S.u.d.sc[j];
      if (c) {
        atomicAdd(&gCnt[arr * CAP + j], c);
        atomicAdd(&gSum[arr * CAP + j], S.u.d.ss[j]);
      }
    }
  }
  gbar(bar, 1);

  // ---- phase E (all blocks, redundant): prefix of hist -> (p, C[p]) sorted
  // by p -> short serial monotone chain -> vertex lv/ls. Identical integers
  // in -> identical results in every block. ----
  int segn[2];
  for (int a2 = 0; a2 < 2; a2++) {
    int cn = tcn[a2];
    for (int j = t; j < cn; j += BS) {
      S.h[j] = cldu(&gCnt[a2 * CAP + j]);
      S.hs[j] = cldull(&gSum[a2 * CAP + j]);
    }
    __syncthreads();
    // wave-0 inclusive prefix (exact integers); count_j = #{x > v_j}
    if (t < 64) {
      int per = (cn + 63) >> 6;
      int beg = t * per, end = beg + per; if (end > cn) end = cn;
      u32 rc = 0; u64 rs = 0;
      for (int j = beg; j < end; j++) {
        rc += S.h[j]; rs += S.hs[j];
        S.h[j] = rc;  S.hs[j] = rs;
      }
      u32 tcv = rc; u64 tsv = rs;
      for (int o = 1; o < 64; o <<= 1) {
        u32 pc = __shfl_up(tcv, o);
        u64 ps = shfl_up_u64(tsv, o);
        if (t >= o) { tcv += pc; tsv += ps; }
      }
      u32 ec = tcv - rc; u64 es = tsv - rs;
      for (int j = beg; j < end; j++) { S.h[j] += ec; S.hs[j] += es; }
    }
    __syncthreads();
    // C[p_j] = S_j/reg - (p*n - p(p-1)/2), in place (exact-in-f64 inputs)
    double* Cv = (double*)S.hs;
    for (int j = t; j < cn; j += BS) {
      double pd = (double)S.h[j];
      double s = (double)(long long)S.hs[j] / SCALE;
      Cv[j] = s / 0.1 - (pd * (double)N_ELEM - pd * (pd - 1.0) * 0.5);
    }
    __syncthreads();
    // serial monotone chain over cn <= ~120 points (in-place stack, write
    // idx <= read idx); prevP skips dup diagram points (empty segments)
    if (t == 0) {
      int top = 0, aX = 0, bX = 0, prevP = -1;
      double cA = 0.0, cB = 0.0;
      for (int k = 0; k < cn; k++) {
        int i = (int)S.h[k];
        if (i == prevP) continue;
        prevP = i;
        double Ci = Cv[k];
        float vi = S.lv[a2][k];
        while (top >= 2) {
          double cr = (double)(bX - aX) * (Ci - cA) - (cB - cA) * (double)(i - aX);
          if (cr >= 0.0) {  // bX on/below chord aX->i : pop
            top--;
            bX = aX; cB = cA;
            if (top >= 2) { aX = (int)S.h[top - 2]; cA = Cv[top - 2]; }
          } else break;
        }
        S.h[top] = (u32)i; Cv[top] = Ci; S.lv[a2][top] = vi;
        aX = bX; cA = cB;
        bX = i;  cB = Ci;
        top++;
      }
      sh_ntop = top;
    }
    __syncthreads();
    {
      int top = sh_ntop;
      for (int k = t; k < top - 1; k += BS)
        S.ls[a2][k] = (Cv[k + 1] - Cv[k]) /
                      (double)((int)S.h[k + 1] - (int)S.h[k]);
      segn[a2] = top - 1;
    }
    __syncthreads();
  }

  // ---- phase F: fused rank + centered moments ----
  // x in segment k iff lv[k] >= x > lv[k+1]; rank = x/reg - slope_k. Mean is
  // analytic: permutahedron projection preserves sum -> mean = (N+1)/2.
  {
    int n0 = segn[0], n1 = segn[1];
    const double m = 0.5 * (double)(N_ELEM + 1);  // 65536.5
    double a0 = 0.0, a1 = 0.0, a2v = 0.0;
    float2 x2 = ((const float2*)(in0 + blk * 1024))[t];
    float2 y2 = ((const float2*)(in1 + blk * 1024))[t];
    float xx[2] = {x2.x, x2.y};
    float yy[2] = {y2.x, y2.y};
#pragma unroll
    for (int e = 0; e < 2; e++) {
      float x = xx[e], y = yy[e];
      int k0 = 0, k1 = 0;
      for (int k = 1; k < n0; k++) if (x <= S.lv[0][k]) k0 = k;
      for (int k = 1; k < n1; k++) if (y <= S.lv[1][k]) k1 = k;
      double ra = (double)x / 0.1 - S.ls[0][k0] - m;
      double rb = (double)y / 0.1 - S.ls[1][k1] - m;
      a0 += ra * rb;
      a1 += ra * ra;
      a2v += rb * rb;
    }
    S.s0[t] = a0; S.s1[t] = a1; S.s2[t] = a2v;
    __syncthreads();
    for (int off = BS / 2; off > 0; off >>= 1) {
      if (t < off) {
        S.s0[t] += S.s0[t + off];
        S.s1[t] += S.s1[t + off];
        S.s2[t] += S.s2[t + off];
      }
      __syncthreads();
    }
    if (t == 0) {
      cstd(&part[blk], S.s0[0]);
      cstd(&part[GRID + blk], S.s1[0]);
      cstd(&part[2 * GRID + blk], S.s2[0]);
    }
  }

  // ---- phase G: last-block-out final reduction ----
  __syncthreads();  // drains t0's part stores (vmcnt waited before s_barrier)
  if (t == 0) {
    u32 old = __hip_atomic_fetch_add(&bar[DONE_OFF], 1u,
                                     __ATOMIC_RELAXED, __HIP_MEMORY_SCOPE_AGENT);
    sh_last = (old == (u32)(GRID - 1)) ? 1 : 0;
  }
  __syncthreads();
  if (sh_last && t < 64) {
    double v0 = 0.0, v1 = 0.0, v2 = 0.0;
    for (int k = t; k < GRID; k += 64) {  // fixed order -> deterministic
      v0 += cldd(&part[k]);
      v1 += cldd(&part[GRID + k]);
      v2 += cldd(&part[2 * GRID + k]);
    }
#pragma unroll
    for (int off = 32; off > 0; off >>= 1) {
      v0 += __shfl_down(v0, off);
      v1 += __shfl_down(v1, off);
      v2 += __shfl_down(v2, off);
    }
    if (t == 0) out[0] = (float)(v0 / (sqrt(v1) * sqrt(v2)));
  }
}

// ---------------- host ----------------
extern "C" void kernel_launch(void* const* d_in, const int* in_sizes, int n_in,
                              void* d_out, int out_size, void* d_ws, size_t ws_size,
                              hipStream_t stream) {
  const float* in0 = (const float*)d_in[0];
  const float* in1 = (const float*)d_in[1];
  float* out = (float*)d_out;

  size_t off = 0;
  char* base = (char*)d_ws;
  auto alloc = [&](size_t bytes) -> char* {
    char* p = base + off;
    off += (bytes + 63) & ~(size_t)63;
    return p;
  };
  // gbits + bar contiguous -> one memset covers both
  u32* gbits = (u32*)alloc(sizeof(u32) * 2 * NW);   // 4096 B (64-aligned)
  u32* bar   = (u32*)alloc(sizeof(u32) * BAR_U32);  // 2432 B
  u32* gCnt  = (u32*)alloc(sizeof(u32) * 2 * CAP);
  u64* gSum  = (u64*)alloc(sizeof(u64) * 2 * CAP);
  double* part = (double*)alloc(sizeof(double) * 3 * GRID);
  (void)ws_size; (void)in_sizes; (void)n_in; (void)out_size;

  // single init memset: occupancy bitmask + barrier tree + done counter
  // (replayed in the graph every iteration -> stateless)
  hipMemsetAsync(gbits, 0, sizeof(u32) * (2 * NW + BAR_U32), stream);

  k_mega<<<dim3(GRID), dim3(BS), 0, stream>>>(
      in0, in1, gbits, bar, gCnt, gSum, part, out);
}